// Round 1
// baseline (176.473 us; speedup 1.0000x reference)
//
#include <hip/hip_runtime.h>

// CPRPackedLinear: out(64x11008) = xperm[:, :1024] @ deq6(W_high) + xperm[:, 1024:] @ deq5(W_low) + bias
//
// Strategy: memory-bound (118 MB of packed int32 weights read once; floor ~19us).
// fp16 MFMA (16x16x32) with weights dequantized tile-by-tile into LDS in
// fragment-ready layout; A (x) pre-permuted+fp16-cast into ws in fragment layout
// so A-frags load directly from global (L2-resident).

#define NFEAT 11008
#define KTOT  4096

typedef _Float16 half8 __attribute__((ext_vector_type(8)));
typedef float    f32x4 __attribute__((ext_vector_type(4)));

// ---------------- prep: x_perm -> fp16 in MFMA A-fragment layout ----------------
// xfrag flat idx = ((s*4 + mt)*64 + lane)*8 + j
//   holds x[m = mt*16 + (lane&15)][ col_indices[k = s*32 + (lane>>4)*8 + j] ]
__global__ __launch_bounds__(256) void prep_xfrag(const float* __restrict__ x,
                                                  const int* __restrict__ col,
                                                  _Float16* __restrict__ xfrag) {
    int idx = blockIdx.x * 256 + threadIdx.x;          // 0..262143
    int j  = idx & 7;
    int l  = (idx >> 3) & 63;
    int mt = (idx >> 9) & 3;
    int s  = idx >> 11;
    int k  = s * 32 + ((l >> 4) << 3) + j;
    int m  = mt * 16 + (l & 15);
    xfrag[idx] = (_Float16)x[m * KTOT + col[k]];
}

// ---------------- main GEMM ----------------
// grid.x = 172 (64-col tiles), grid.y = 4 (K chunks of 1024: chunk0=6bit high, 1..3=5bit low)
__global__ __launch_bounds__(256) void gemm_kernel(const int* __restrict__ Wh,
                                                   const int* __restrict__ Wl,
                                                   const float* __restrict__ sh,
                                                   const float* __restrict__ sl,
                                                   const _Float16* __restrict__ xfrag,
                                                   float* __restrict__ dst,
                                                   int atomic_mode) {
    const int n0   = blockIdx.x * 64;
    const int kc   = blockIdx.y;
    const int tid  = threadIdx.x;
    const int lane = tid & 63;
    const int wave = tid >> 6;

    // B fragments in LDS, fragment-ready: frag (nt, q), lane L at
    //   half-offset (((nt*2+q)*64 + L) + nt)*8   (the +nt*16B skew spreads the
    //   dequant ds_write_b128s evenly over all 8 bank-quads)
    __shared__ _Float16 Wfrag[8 * 64 * 8 + 4 * 8];

    f32x4 acc[4];
#pragma unroll
    for (int i = 0; i < 4; ++i) acc[i] = (f32x4){0.f, 0.f, 0.f, 0.f};

    const int col  = lane;       // dequant column this thread owns (coalesced global loads)
    const int nt   = col >> 4;
    const int n_in = col & 15;

    for (int t = 0; t < 16; ++t) {
        if (kc == 0) {
            // ---- 6-bit region: groups of 4 values from 3 packed ints ----
            const float s = sh[(t >> 1) * NFEAT + n0 + col];
#pragma unroll
            for (int p = 0; p < 2; ++p) {
                const int kg2 = p * 4 + wave;          // 0..7, k' = 8*kg2
                const int k   = t * 64 + kg2 * 8;      // row in high region
                const int G   = k >> 2;                // group-of-4 index
                const int* bp = Wh + (3 * G) * NFEAT + n0 + col;
                int b0 = bp[0],         b1 = bp[NFEAT],     b2 = bp[2 * NFEAT];
                int b3 = bp[3 * NFEAT], b4 = bp[4 * NFEAT], b5 = bp[5 * NFEAT];
                int v[8];
                v[0] = b0 & 63;
                v[1] = ((b0 >> 6) & 3) | ((b1 & 15) << 2);
                v[2] = ((b1 >> 4) & 15) | ((b2 & 3) << 4);
                v[3] = (b2 >> 2) & 63;
                v[4] = b3 & 63;
                v[5] = ((b3 >> 6) & 3) | ((b4 & 15) << 2);
                v[6] = ((b4 >> 4) & 15) | ((b5 & 3) << 4);
                v[7] = (b5 >> 2) & 63;
                half8 w;
#pragma unroll
                for (int j = 0; j < 8; ++j) w[j] = (_Float16)(((float)v[j] - 31.0f) * s);
                const int q = kg2 >> 2, quad = kg2 & 3;
                const int off = (((nt * 2 + q) * 64 + quad * 16 + n_in) + nt) * 8;
                *(half8*)&Wfrag[off] = w;
            }
        } else {
            // ---- 5-bit region: groups of 8 values from 5 packed ints ----
            const int kl0 = (kc - 1) * 1024 + t * 64;
            const float s = sl[(kl0 >> 7) * NFEAT + n0 + col];
#pragma unroll
            for (int p = 0; p < 2; ++p) {
                const int kg8 = p * 4 + wave;          // 0..7
                const int kl  = kl0 + kg8 * 8;         // row in low region
                const int G   = kl >> 3;               // group-of-8 index
                const int* bp = Wl + (5 * G) * NFEAT + n0 + col;
                int b0 = bp[0], b1 = bp[NFEAT], b2 = bp[2 * NFEAT];
                int b3 = bp[3 * NFEAT], b4 = bp[4 * NFEAT];
                int v[8];
                v[0] = b0 & 31;
                v[1] = ((b0 >> 5) & 7) | ((b1 & 3) << 3);
                v[2] = (b1 >> 2) & 31;
                v[3] = ((b1 >> 7) & 1) | ((b2 & 15) << 1);
                v[4] = ((b2 >> 4) & 15) | ((b3 & 1) << 4);
                v[5] = (b3 >> 1) & 31;
                v[6] = ((b3 >> 6) & 3) | ((b4 & 7) << 2);
                v[7] = (b4 >> 3) & 31;
                half8 w;
#pragma unroll
                for (int j = 0; j < 8; ++j) w[j] = (_Float16)(((float)v[j] - 15.0f) * s);
                const int q = kg8 >> 2, quad = kg8 & 3;
                const int off = (((nt * 2 + q) * 64 + quad * 16 + n_in) + nt) * 8;
                *(half8*)&Wfrag[off] = w;
            }
        }
        __syncthreads();

        // ---- MFMA: wave w owns m rows [16w, 16w+16), all 64 n cols ----
#pragma unroll
        for (int q = 0; q < 2; ++q) {
            const int sg = kc * 32 + t * 2 + q;        // global k-step
            half8 a = *(const half8*)(xfrag + (((sg * 4 + wave) * 64 + lane) << 3));
#pragma unroll
            for (int j = 0; j < 4; ++j) {
                half8 b = *(half8*)&Wfrag[(((j * 2 + q) * 64 + lane) + j) * 8];
                acc[j] = __builtin_amdgcn_mfma_f32_16x16x32_f16(a, b, acc[j], 0, 0, 0);
            }
        }
        __syncthreads();
    }

    // ---- epilogue: D row = (lane>>4)*4 + r, col = lane&15 ----
    const int rb = wave * 16 + ((lane >> 4) << 2);
    const int cb = lane & 15;
    if (atomic_mode) {
#pragma unroll
        for (int j = 0; j < 4; ++j)
#pragma unroll
            for (int r = 0; r < 4; ++r)
                atomicAdd(&dst[(rb + r) * NFEAT + n0 + j * 16 + cb], acc[j][r]);
    } else {
        float* base = dst + (size_t)kc * 64 * NFEAT;
#pragma unroll
        for (int j = 0; j < 4; ++j)
#pragma unroll
            for (int r = 0; r < 4; ++r)
                base[(rb + r) * NFEAT + n0 + j * 16 + cb] = acc[j][r];
    }
}

// ---------------- reduce: out = bias + sum_kc partial[kc] ----------------
__global__ __launch_bounds__(256) void reduce_out(const float* __restrict__ part,
                                                  const float* __restrict__ bias,
                                                  float* __restrict__ out) {
    const int idx = blockIdx.x * 256 + threadIdx.x;    // 0..176127 (float4 units)
    const int f   = idx * 4;
    const int n   = f % NFEAT;                          // NFEAT % 4 == 0 -> same row
    f32x4 a = *(const f32x4*)(part + f);
    f32x4 b = *(const f32x4*)(part + 704512 + f);
    f32x4 c = *(const f32x4*)(part + 2 * 704512 + f);
    f32x4 d = *(const f32x4*)(part + 3 * 704512 + f);
    f32x4 bi = *(const f32x4*)(bias + n);
    *(f32x4*)(out + f) = a + b + c + d + bi;
}

__global__ __launch_bounds__(256) void init_bias(const float* __restrict__ bias,
                                                 float* __restrict__ out) {
    const int idx = blockIdx.x * 256 + threadIdx.x;    // 0..704511
    out[idx] = bias[idx % NFEAT];
}

extern "C" void kernel_launch(void* const* d_in, const int* in_sizes, int n_in,
                              void* d_out, int out_size, void* d_ws, size_t ws_size,
                              hipStream_t stream) {
    const float* x    = (const float*)d_in[0];
    const int*   Wh   = (const int*)d_in[1];
    const int*   Wl   = (const int*)d_in[2];
    const float* sh   = (const float*)d_in[3];
    const float* sl   = (const float*)d_in[4];
    const int*   col  = (const int*)d_in[5];
    const float* bias = (const float*)d_in[6];
    float* out = (float*)d_out;

    _Float16* xfrag = (_Float16*)d_ws;                 // 512 KB
    const size_t xfrag_bytes = 64 * KTOT * sizeof(_Float16);
    const size_t part_bytes  = 4ull * 64 * NFEAT * sizeof(float);   // 11.27 MB

    prep_xfrag<<<1024, 256, 0, stream>>>(x, col, xfrag);

    dim3 grid(172, 4);
    if (ws_size >= xfrag_bytes + part_bytes) {
        float* part = (float*)((char*)d_ws + xfrag_bytes);
        gemm_kernel<<<grid, 256, 0, stream>>>(Wh, Wl, sh, sl, xfrag, part, 0);
        reduce_out<<<688, 256, 0, stream>>>(part, bias, out);
    } else {
        init_bias<<<2752, 256, 0, stream>>>(bias, out);
        gemm_kernel<<<grid, 256, 0, stream>>>(Wh, Wl, sh, sl, xfrag, out, 1);
    }
}